// Round 1
// baseline (3884.691 us; speedup 1.0000x reference)
//
#include <hip/hip_runtime.h>
#include <math.h>

#define N_ATOMS 51200
#define M_NBR   12
#define NBRF    41
#define FDIM    64
#define HDIM    128
#define NCRYS   128
#define APC     400
#define EPS_BN  1e-5f
#define NBLK_CONV 1600   // 32 atoms / block
#define NBLK_EMB  800    // 64 atoms / block

__device__ __forceinline__ int rfl(int v) { return __builtin_amdgcn_readfirstlane(v); }
__device__ __forceinline__ float sp_f(float z) {
  // softplus = logaddexp(z, 0) = max(z,0) + log1p(exp(-|z|))  (matches jax.nn.softplus)
  return fmaxf(z, 0.f) + log1pf(expf(-fabsf(z)));
}

// x = atom_fea @ embW + embb   (N x 92) @ (92 x 64)
__global__ __launch_bounds__(256) void k_embed(const float* __restrict__ afea,
    const float* __restrict__ embW, const float* __restrict__ embb,
    float* __restrict__ x) {
  const int lane = threadIdx.x & 63;
  const int grp  = rfl((int)(threadIdx.x >> 6));   // 0..3, wave-uniform
  float w[92];
  #pragma unroll
  for (int k = 0; k < 92; ++k) w[k] = embW[k * FDIM + lane];
  const float bias = embb[lane];
  const int n0 = blockIdx.x * 64 + grp * 16;
  for (int i = 0; i < 16; ++i) {
    const int n = n0 + i;
    const float* ar = afea + n * 92;
    float acc = bias;
    #pragma unroll
    for (int k = 0; k < 92; ++k) acc = fmaf(ar[k], w[k], acc);
    x[n * FDIM + lane] = acc;
  }
}

// u = x @ W[0:64,:]   v = x @ W[64:128,:]    (N x 64) @ (64 x 128) each
__global__ __launch_bounds__(256) void k_uv(const float* __restrict__ x,
    const float* __restrict__ W, float* __restrict__ u, float* __restrict__ v) {
  const int t = threadIdx.x;
  const int c = t & 127;
  const int half = rfl(t >> 7);          // 0 -> u, 1 -> v (wave-uniform)
  float w[64];
  const float* Wb = W + half * 64 * HDIM;
  #pragma unroll
  for (int k = 0; k < 64; ++k) w[k] = Wb[k * HDIM + c];
  float* outp = half ? v : u;
  const int n0 = blockIdx.x * 128;
  for (int i = 0; i < 128; ++i) {
    const int n = n0 + i;
    const float* xr = x + n * FDIM;
    float acc = 0.f;
    #pragma unroll
    for (int k = 0; k < 64; ++k) acc = fmaf(xr[k], w[k], acc);
    outp[n * HDIM + c] = acc;
  }
}

// Conv main passes. g_raw[n,m,c] = u[n,c] + v[j(n,m),c] + (e[n,m,:] @ W2)[c]
// P1 (IS_P2=false): per-column sum / sumsq of g_raw -> partials (fcb cancels in BN).
// P2 (IS_P2=true):  normalize (scale/shift fold BN1+bias), sigmoid(filter)*softplus(core),
//                   sum over m -> summed; also per-column sum/sumsq of summed.
template<bool IS_P2>
__global__ __launch_bounds__(256) void k_conv(const float* __restrict__ u,
    const float* __restrict__ v, const float* __restrict__ e,
    const int* __restrict__ idx, const float* __restrict__ W,
    const float* __restrict__ sc1, float* __restrict__ summed,
    float* __restrict__ partials) {
  const int lane = threadIdx.x & 63;
  const int grp  = rfl((int)(threadIdx.x >> 6));   // 0..3
  float wlo[NBRF], whi[NBRF];
  const float* W2 = W + 128 * HDIM;
  #pragma unroll
  for (int k = 0; k < NBRF; ++k) {
    wlo[k] = W2[k * HDIM + lane];
    whi[k] = W2[k * HDIM + 64 + lane];
  }
  float sc_lo = 0.f, sh_lo = 0.f, sc_hi = 0.f, sh_hi = 0.f;
  if constexpr (IS_P2) {
    sc_lo = sc1[lane];       sc_hi = sc1[64 + lane];
    sh_lo = sc1[128 + lane]; sh_hi = sc1[192 + lane];
  }
  float a0 = 0.f, a1 = 0.f, a2 = 0.f, a3 = 0.f;
  const int n0 = blockIdx.x * 32 + grp * 8;
  for (int i = 0; i < 8; ++i) {
    const int n = n0 + i;
    const float u_lo = u[n * HDIM + lane];
    const float u_hi = u[n * HDIM + 64 + lane];
    const int* jrow = idx + n * M_NBR;
    const float* erow = e + n * M_NBR * NBRF;
    float smd = 0.f;
    for (int m = 0; m < M_NBR; ++m) {
      const int j = rfl(jrow[m]);
      const float vl = v[j * HDIM + lane];
      const float vh = v[j * HDIM + 64 + lane];
      const float* er = erow + m * NBRF;
      float g_lo = u_lo + vl;
      float g_hi = u_hi + vh;
      #pragma unroll
      for (int k = 0; k < NBRF; ++k) {
        const float ek = er[k];
        g_lo = fmaf(ek, wlo[k], g_lo);
        g_hi = fmaf(ek, whi[k], g_hi);
      }
      if constexpr (!IS_P2) {
        a0 += g_lo; a1 = fmaf(g_lo, g_lo, a1);
        a2 += g_hi; a3 = fmaf(g_hi, g_hi, a3);
      } else {
        const float nlo = fmaf(g_lo, sc_lo, sh_lo);
        const float nhi = fmaf(g_hi, sc_hi, sh_hi);
        const float sig = 1.f / (1.f + expf(-nlo));
        smd = fmaf(sig, sp_f(nhi), smd);
      }
    }
    if constexpr (IS_P2) {
      summed[n * FDIM + lane] = smd;
      a0 += smd; a1 = fmaf(smd, smd, a1);
    }
  }
  __shared__ float red[4][256];
  if constexpr (!IS_P2) {
    red[grp][lane]       = a0;   // sum, cols 0..63
    red[grp][64 + lane]  = a2;   // sum, cols 64..127
    red[grp][128 + lane] = a1;   // sumsq, cols 0..63
    red[grp][192 + lane] = a3;   // sumsq, cols 64..127
    __syncthreads();
    const int t = threadIdx.x;
    partials[blockIdx.x * 256 + t] = red[0][t] + red[1][t] + red[2][t] + red[3][t];
  } else {
    red[grp][lane]      = a0;    // sum of summed, col=lane
    red[grp][64 + lane] = a1;    // sumsq
    __syncthreads();
    const int t = threadIdx.x;
    if (t < 128)
      partials[blockIdx.x * 128 + t] = red[0][t] + red[1][t] + red[2][t] + red[3][t];
  }
}

// Reduce partials -> scale/shift for BN1 (128 cols). normalized = g_raw*scale + shift.
__global__ __launch_bounds__(64) void k_bn1(const float* __restrict__ part,
    const float* __restrict__ g1, const float* __restrict__ b1,
    float* __restrict__ sc1) {
  const int col = blockIdx.x;
  const int lane = threadIdx.x;
  double s = 0.0, q = 0.0;
  for (int b = lane; b < NBLK_CONV; b += 64) {
    s += (double)part[b * 256 + col];
    q += (double)part[b * 256 + 128 + col];
  }
  #pragma unroll
  for (int off = 32; off; off >>= 1) {
    s += __shfl_down(s, off);
    q += __shfl_down(q, off);
  }
  if (lane == 0) {
    const double NM = (double)N_ATOMS * (double)M_NBR;
    const double mean = s / NM;
    const double var = q / NM - mean * mean;
    const float inv = rsqrtf((float)var + EPS_BN);
    const float scale = g1[col] * inv;
    sc1[col] = scale;
    sc1[128 + col] = b1[col] - (float)mean * scale;
  }
}

__global__ __launch_bounds__(64) void k_bn2(const float* __restrict__ part,
    const float* __restrict__ g2, const float* __restrict__ b2,
    float* __restrict__ sc2) {
  const int col = blockIdx.x;   // 0..63
  const int lane = threadIdx.x;
  double s = 0.0, q = 0.0;
  for (int b = lane; b < NBLK_CONV; b += 64) {
    s += (double)part[b * 128 + col];
    q += (double)part[b * 128 + 64 + col];
  }
  #pragma unroll
  for (int off = 32; off; off >>= 1) {
    s += __shfl_down(s, off);
    q += __shfl_down(q, off);
  }
  if (lane == 0) {
    const double Nd = (double)N_ATOMS;
    const double mean = s / Nd;
    const double var = q / Nd - mean * mean;
    const float inv = rsqrtf((float)var + EPS_BN);
    const float scale = g2[col] * inv;
    sc2[col] = scale;
    sc2[64 + col] = b2[col] - (float)mean * scale;
  }
}

// x = softplus(x + summed*scale2 + shift2), float4-vectorized
__global__ __launch_bounds__(256) void k_p3(float* __restrict__ x,
    const float* __restrict__ summed, const float* __restrict__ sc2) {
  const int i = blockIdx.x * 256 + threadIdx.x;
  const int base = i * 4;
  const int c0 = base & 63;
  float4 xv = *(const float4*)(x + base);
  const float4 sv = *(const float4*)(summed + base);
  const float4 sc = *(const float4*)(sc2 + c0);
  const float4 sh = *(const float4*)(sc2 + 64 + c0);
  xv.x = sp_f(xv.x + fmaf(sv.x, sc.x, sh.x));
  xv.y = sp_f(xv.y + fmaf(sv.y, sc.y, sh.y));
  xv.z = sp_f(xv.z + fmaf(sv.z, sc.z, sh.z));
  xv.w = sp_f(xv.w + fmaf(sv.w, sc.w, sh.w));
  *(float4*)(x + base) = xv;
}

// pooled = mean over 400 atoms; cOut = softplus(pooled @ denseW + denseb)
__global__ __launch_bounds__(128) void k_pool(const float* __restrict__ x,
    const int* __restrict__ cidx, const float* __restrict__ denseW,
    const float* __restrict__ denseb, float* __restrict__ cOut) {
  __shared__ float ps[128];
  const int c = blockIdx.x;
  const int t = threadIdx.x;
  const int f = t & 63;
  const int h = rfl(t >> 6);    // 0 or 1 (wave-uniform)
  const int* row = cidx + c * APC + h * 200;
  float acc = 0.f;
  for (int a = 0; a < 200; ++a) {
    const int id = row[a];
    acc += x[id * FDIM + f];
  }
  ps[t] = acc;
  __syncthreads();
  if (t < 64) ps[t] = (ps[t] + ps[64 + t]) * (1.f / (float)APC);
  __syncthreads();
  float acch = denseb[t];
  #pragma unroll 8
  for (int k = 0; k < 64; ++k) acch = fmaf(ps[k], denseW[k * HDIM + t], acch);
  cOut[c * HDIM + t] = sp_f(acch);
}

// crys = |cA-cB|; t = softplus(crys@ffW + ffb); out = t @ outW + outb
__global__ __launch_bounds__(128) void k_final(const float* __restrict__ cA,
    const float* __restrict__ cB, const float* __restrict__ ffW,
    const float* __restrict__ ffb, const float* __restrict__ outW,
    const float* __restrict__ outb, float* __restrict__ out) {
  __shared__ float cr[128];
  __shared__ float red2[2];
  const int c = blockIdx.x, t = threadIdx.x;
  cr[t] = fabsf(cA[c * HDIM + t] - cB[c * HDIM + t]);
  __syncthreads();
  float acc = ffb[t];
  #pragma unroll 8
  for (int k = 0; k < 128; ++k) acc = fmaf(cr[k], ffW[k * HDIM + t], acc);
  float val = sp_f(acc) * outW[t];
  #pragma unroll
  for (int off = 32; off; off >>= 1) val += __shfl_down(val, off);
  if ((t & 63) == 0) red2[t >> 6] = val;
  __syncthreads();
  if (t == 0) out[c] = red2[0] + red2[1] + outb[0];
}

extern "C" void kernel_launch(void* const* d_in, const int* in_sizes, int n_in,
                              void* d_out, int out_size, void* d_ws, size_t ws_size,
                              hipStream_t stream) {
  const float* afeaA = (const float*)d_in[0];
  const float* eA    = (const float*)d_in[1];
  const int*   idxA  = (const int*)d_in[2];
  const int*   cidxA = (const int*)d_in[3];
  const float* afeaB = (const float*)d_in[4];
  const float* eB    = (const float*)d_in[5];
  const int*   idxB  = (const int*)d_in[6];
  const int*   cidxB = (const int*)d_in[7];
  const float* embW  = (const float*)d_in[8];
  const float* embb  = (const float*)d_in[9];
  const float* fcW   = (const float*)d_in[10];
  // d_in[11] = fcb: cancels exactly inside BN1 (affine-then-BN), unused.
  const float* bn1g  = (const float*)d_in[12];
  const float* bn1b  = (const float*)d_in[13];
  const float* bn2g  = (const float*)d_in[14];
  const float* bn2b  = (const float*)d_in[15];
  const float* denseW = (const float*)d_in[16];
  const float* denseb = (const float*)d_in[17];
  const float* ffW   = (const float*)d_in[18];
  const float* ffb   = (const float*)d_in[19];
  const float* outW  = (const float*)d_in[20];
  const float* outb  = (const float*)d_in[21];

  char* w = (char*)d_ws;
  float* x      = (float*)w; w += (size_t)N_ATOMS * FDIM * 4;   // 13.1 MB
  float* u      = (float*)w; w += (size_t)N_ATOMS * HDIM * 4;   // 26.2 MB
  float* v      = (float*)w; w += (size_t)N_ATOMS * HDIM * 4;   // 26.2 MB
  float* summed = (float*)w; w += (size_t)N_ATOMS * FDIM * 4;   // 13.1 MB
  float* part1  = (float*)w; w += (size_t)NBLK_CONV * 256 * 4;  // 1.6 MB
  float* part2  = (float*)w; w += (size_t)NBLK_CONV * 128 * 4;  // 0.8 MB
  float* sc1    = (float*)w; w += 256 * 4;
  float* sc2    = (float*)w; w += 128 * 4;
  float* cA     = (float*)w; w += 128 * 128 * 4;
  float* cB     = (float*)w; w += 128 * 128 * 4;
  (void)ws_size; (void)in_sizes; (void)n_in; (void)out_size;

  for (int br = 0; br < 2; ++br) {
    const float* afea = br ? afeaB : afeaA;
    const float* e    = br ? eB : eA;
    const int*   idx  = br ? idxB : idxA;
    const int*   cidx = br ? cidxB : cidxA;
    float* cOut = br ? cB : cA;
    k_embed<<<NBLK_EMB, 256, 0, stream>>>(afea, embW, embb, x);
    for (int L = 0; L < 3; ++L) {
      const float* W = fcW + (size_t)L * 169 * HDIM;
      k_uv<<<400, 256, 0, stream>>>(x, W, u, v);
      k_conv<false><<<NBLK_CONV, 256, 0, stream>>>(u, v, e, idx, W, nullptr, nullptr, part1);
      k_bn1<<<128, 64, 0, stream>>>(part1, bn1g + L * 128, bn1b + L * 128, sc1);
      k_conv<true><<<NBLK_CONV, 256, 0, stream>>>(u, v, e, idx, W, sc1, summed, part2);
      k_bn2<<<64, 64, 0, stream>>>(part2, bn2g + L * 64, bn2b + L * 64, sc2);
      k_p3<<<3200, 256, 0, stream>>>(x, summed, sc2);
    }
    k_pool<<<NCRYS, 128, 0, stream>>>(x, cidx, denseW, denseb, cOut);
  }
  k_final<<<NCRYS, 128, 0, stream>>>(cA, cB, ffW, ffb, outW, outb, (float*)d_out);
}

// Round 3
// 3863.770 us; speedup vs baseline: 1.0054x; 1.0054x over previous
//
#include <hip/hip_runtime.h>
#include <math.h>

#define N_ATOMS 51200
#define M_NBR   12
#define NBRF    41
#define FDIM    64
#define HDIM    128
#define NCRYS   128
#define APC     400
#define EPS_BN  1e-5f
#define NBLK_CONV 1600   // 32 atoms / block
#define NBLK_EMB  800    // 64 atoms / block

__device__ __forceinline__ int rfl(int v) { return __builtin_amdgcn_readfirstlane(v); }
__device__ __forceinline__ float sp_f(float z) {
  // softplus = logaddexp(z, 0) = max(z,0) + log1p(exp(-|z|))  (matches jax.nn.softplus)
  return fmaxf(z, 0.f) + log1pf(expf(-fabsf(z)));
}

#define REP41(X) X(0) X(1) X(2) X(3) X(4) X(5) X(6) X(7) X(8) X(9) \
                 X(10) X(11) X(12) X(13) X(14) X(15) X(16) X(17) X(18) X(19) \
                 X(20) X(21) X(22) X(23) X(24) X(25) X(26) X(27) X(28) X(29) \
                 X(30) X(31) X(32) X(33) X(34) X(35) X(36) X(37) X(38) X(39) X(40)

// x = atom_fea @ embW + embb   (N x 92) @ (92 x 64)
// launch_bounds(,2): cap occupancy target at 2 waves/EU so the 92-deep weight
// set stays register-resident (default 8-wave target spills it to scratch).
__global__ __launch_bounds__(256, 2) void k_embed(const float* __restrict__ afea,
    const float* __restrict__ embW, const float* __restrict__ embb,
    float* __restrict__ x) {
  const int lane = threadIdx.x & 63;
  const int grp  = rfl((int)(threadIdx.x >> 6));   // 0..3, wave-uniform
  float w[92];
  #pragma unroll
  for (int k = 0; k < 92; ++k) w[k] = embW[k * FDIM + lane];
  const float bias = embb[lane];
  const int n0 = blockIdx.x * 64 + grp * 16;
  for (int i = 0; i < 16; ++i) {
    const int n = n0 + i;
    const float* ar = afea + n * 92;
    float acc = bias;
    #pragma unroll
    for (int k = 0; k < 92; ++k) acc = fmaf(ar[k], w[k], acc);
    x[n * FDIM + lane] = acc;
  }
}

// u = x @ W[0:64,:]   v = x @ W[64:128,:]    (N x 64) @ (64 x 128) each
__global__ __launch_bounds__(256, 2) void k_uv(const float* __restrict__ x,
    const float* __restrict__ W, float* __restrict__ u, float* __restrict__ v) {
  const int t = threadIdx.x;
  const int c = t & 127;
  const int half = rfl(t >> 7);          // 0 -> u, 1 -> v (wave-uniform)
  float w[64];
  const float* Wb = W + half * 64 * HDIM;
  #pragma unroll
  for (int k = 0; k < 64; ++k) w[k] = Wb[k * HDIM + c];
  float* outp = half ? v : u;
  const int n0 = blockIdx.x * 128;
  for (int i = 0; i < 128; ++i) {
    const int n = n0 + i;
    const float* xr = x + n * FDIM;
    float acc = 0.f;
    #pragma unroll
    for (int k = 0; k < 64; ++k) acc = fmaf(xr[k], w[k], acc);
    outp[n * HDIM + c] = acc;
  }
}

// Conv main passes. g_raw[n,m,c] = u[n,c] + v[j(n,m),c] + (e[n,m,:] @ W2)[c]
// P1 (IS_P2=false): per-column sum / sumsq of g_raw -> partials (fcb cancels in BN).
// P2 (IS_P2=true):  normalize (scale/shift fold BN1+bias), sigmoid(filter)*softplus(core),
//                   sum over m -> summed; also per-column sum/sumsq of summed.
// Weights held as 82 NAMED scalars (macro) + launch_bounds(,2): guarantees
// register residency (round-1 build spilled them chasing 8 waves/EU, VGPR=60).
template<bool IS_P2>
__global__ __launch_bounds__(256, 2) void k_conv(const float* __restrict__ u,
    const float* __restrict__ v, const float* __restrict__ e,
    const int* __restrict__ idx, const float* __restrict__ W,
    const float* __restrict__ sc1, float* __restrict__ summed,
    float* __restrict__ partials) {
  const int lane = threadIdx.x & 63;
  const int grp  = rfl((int)(threadIdx.x >> 6));   // 0..3
  const float* W2 = W + 128 * HDIM;
#define DECL_W(i) float wl##i = W2[i * HDIM + lane], wh##i = W2[i * HDIM + 64 + lane];
  REP41(DECL_W)
#undef DECL_W
  float sc_lo = 0.f, sh_lo = 0.f, sc_hi = 0.f, sh_hi = 0.f;
  if constexpr (IS_P2) {
    sc_lo = sc1[lane];       sc_hi = sc1[64 + lane];
    sh_lo = sc1[128 + lane]; sh_hi = sc1[192 + lane];
  }
  float a0 = 0.f, a1 = 0.f, a2 = 0.f, a3 = 0.f;
  const int n0 = blockIdx.x * 32 + grp * 8;
  for (int i = 0; i < 8; ++i) {
    const int n = n0 + i;
    const float u_lo = u[n * HDIM + lane];
    const float u_hi = u[n * HDIM + 64 + lane];
    const int* jrow = idx + n * M_NBR;
    const float* erow = e + n * M_NBR * NBRF;
    float smd = 0.f;
    for (int m = 0; m < M_NBR; ++m) {
      const int j = rfl(jrow[m]);
      const float vl = v[j * HDIM + lane];
      const float vh = v[j * HDIM + 64 + lane];
      const float* er = erow + m * NBRF;
      float g_lo = u_lo + vl;
      float g_hi = u_hi + vh;
#define FMA_K(i) { const float ek##i = er[i]; \
                   g_lo = fmaf(ek##i, wl##i, g_lo); \
                   g_hi = fmaf(ek##i, wh##i, g_hi); }
      REP41(FMA_K)
#undef FMA_K
      if constexpr (!IS_P2) {
        a0 += g_lo; a1 = fmaf(g_lo, g_lo, a1);
        a2 += g_hi; a3 = fmaf(g_hi, g_hi, a3);
      } else {
        const float nlo = fmaf(g_lo, sc_lo, sh_lo);
        const float nhi = fmaf(g_hi, sc_hi, sh_hi);
        const float sig = 1.f / (1.f + expf(-nlo));
        smd = fmaf(sig, sp_f(nhi), smd);
      }
    }
    if constexpr (IS_P2) {
      summed[n * FDIM + lane] = smd;
      a0 += smd; a1 = fmaf(smd, smd, a1);
    }
  }
  __shared__ float red[4][256];
  if constexpr (!IS_P2) {
    red[grp][lane]       = a0;   // sum, cols 0..63
    red[grp][64 + lane]  = a2;   // sum, cols 64..127
    red[grp][128 + lane] = a1;   // sumsq, cols 0..63
    red[grp][192 + lane] = a3;   // sumsq, cols 64..127
    __syncthreads();
    const int t = threadIdx.x;
    partials[blockIdx.x * 256 + t] = red[0][t] + red[1][t] + red[2][t] + red[3][t];
  } else {
    red[grp][lane]      = a0;    // sum of summed, col=lane
    red[grp][64 + lane] = a1;    // sumsq
    __syncthreads();
    const int t = threadIdx.x;
    if (t < 128)
      partials[blockIdx.x * 128 + t] = red[0][t] + red[1][t] + red[2][t] + red[3][t];
  }
}

// Reduce partials -> scale/shift for BN1 (128 cols). normalized = g_raw*scale + shift.
__global__ __launch_bounds__(64) void k_bn1(const float* __restrict__ part,
    const float* __restrict__ g1, const float* __restrict__ b1,
    float* __restrict__ sc1) {
  const int col = blockIdx.x;
  const int lane = threadIdx.x;
  double s = 0.0, q = 0.0;
  for (int b = lane; b < NBLK_CONV; b += 64) {
    s += (double)part[b * 256 + col];
    q += (double)part[b * 256 + 128 + col];
  }
  #pragma unroll
  for (int off = 32; off; off >>= 1) {
    s += __shfl_down(s, off);
    q += __shfl_down(q, off);
  }
  if (lane == 0) {
    const double NM = (double)N_ATOMS * (double)M_NBR;
    const double mean = s / NM;
    const double var = q / NM - mean * mean;
    const float inv = rsqrtf((float)var + EPS_BN);
    const float scale = g1[col] * inv;
    sc1[col] = scale;
    sc1[128 + col] = b1[col] - (float)mean * scale;
  }
}

__global__ __launch_bounds__(64) void k_bn2(const float* __restrict__ part,
    const float* __restrict__ g2, const float* __restrict__ b2,
    float* __restrict__ sc2) {
  const int col = blockIdx.x;   // 0..63
  const int lane = threadIdx.x;
  double s = 0.0, q = 0.0;
  for (int b = lane; b < NBLK_CONV; b += 64) {
    s += (double)part[b * 128 + col];
    q += (double)part[b * 128 + 64 + col];
  }
  #pragma unroll
  for (int off = 32; off; off >>= 1) {
    s += __shfl_down(s, off);
    q += __shfl_down(q, off);
  }
  if (lane == 0) {
    const double Nd = (double)N_ATOMS;
    const double mean = s / Nd;
    const double var = q / Nd - mean * mean;
    const float inv = rsqrtf((float)var + EPS_BN);
    const float scale = g2[col] * inv;
    sc2[col] = scale;
    sc2[64 + col] = b2[col] - (float)mean * scale;
  }
}

// x = softplus(x + summed*scale2 + shift2), float4-vectorized
__global__ __launch_bounds__(256) void k_p3(float* __restrict__ x,
    const float* __restrict__ summed, const float* __restrict__ sc2) {
  const int i = blockIdx.x * 256 + threadIdx.x;
  const int base = i * 4;
  const int c0 = base & 63;
  float4 xv = *(const float4*)(x + base);
  const float4 sv = *(const float4*)(summed + base);
  const float4 sc = *(const float4*)(sc2 + c0);
  const float4 sh = *(const float4*)(sc2 + 64 + c0);
  xv.x = sp_f(xv.x + fmaf(sv.x, sc.x, sh.x));
  xv.y = sp_f(xv.y + fmaf(sv.y, sc.y, sh.y));
  xv.z = sp_f(xv.z + fmaf(sv.z, sc.z, sh.z));
  xv.w = sp_f(xv.w + fmaf(sv.w, sc.w, sh.w));
  *(float4*)(x + base) = xv;
}

// pooled = mean over 400 atoms; cOut = softplus(pooled @ denseW + denseb)
__global__ __launch_bounds__(128) void k_pool(const float* __restrict__ x,
    const int* __restrict__ cidx, const float* __restrict__ denseW,
    const float* __restrict__ denseb, float* __restrict__ cOut) {
  __shared__ float ps[128];
  const int c = blockIdx.x;
  const int t = threadIdx.x;
  const int f = t & 63;
  const int h = rfl(t >> 6);    // 0 or 1 (wave-uniform)
  const int* row = cidx + c * APC + h * 200;
  float acc = 0.f;
  for (int a = 0; a < 200; ++a) {
    const int id = row[a];
    acc += x[id * FDIM + f];
  }
  ps[t] = acc;
  __syncthreads();
  if (t < 64) ps[t] = (ps[t] + ps[64 + t]) * (1.f / (float)APC);
  __syncthreads();
  float acch = denseb[t];
  #pragma unroll 8
  for (int k = 0; k < 64; ++k) acch = fmaf(ps[k], denseW[k * HDIM + t], acch);
  cOut[c * HDIM + t] = sp_f(acch);
}

// crys = |cA-cB|; t = softplus(crys@ffW + ffb); out = t @ outW + outb
__global__ __launch_bounds__(128) void k_final(const float* __restrict__ cA,
    const float* __restrict__ cB, const float* __restrict__ ffW,
    const float* __restrict__ ffb, const float* __restrict__ outW,
    const float* __restrict__ outb, float* __restrict__ out) {
  __shared__ float cr[128];
  __shared__ float red2[2];
  const int c = blockIdx.x, t = threadIdx.x;
  cr[t] = fabsf(cA[c * HDIM + t] - cB[c * HDIM + t]);
  __syncthreads();
  float acc = ffb[t];
  #pragma unroll 8
  for (int k = 0; k < 128; ++k) acc = fmaf(cr[k], ffW[k * HDIM + t], acc);
  float val = sp_f(acc) * outW[t];
  #pragma unroll
  for (int off = 32; off; off >>= 1) val += __shfl_down(val, off);
  if ((t & 63) == 0) red2[t >> 6] = val;
  __syncthreads();
  if (t == 0) out[c] = red2[0] + red2[1] + outb[0];
}

extern "C" void kernel_launch(void* const* d_in, const int* in_sizes, int n_in,
                              void* d_out, int out_size, void* d_ws, size_t ws_size,
                              hipStream_t stream) {
  const float* afeaA = (const float*)d_in[0];
  const float* eA    = (const float*)d_in[1];
  const int*   idxA  = (const int*)d_in[2];
  const int*   cidxA = (const int*)d_in[3];
  const float* afeaB = (const float*)d_in[4];
  const float* eB    = (const float*)d_in[5];
  const int*   idxB  = (const int*)d_in[6];
  const int*   cidxB = (const int*)d_in[7];
  const float* embW  = (const float*)d_in[8];
  const float* embb  = (const float*)d_in[9];
  const float* fcW   = (const float*)d_in[10];
  // d_in[11] = fcb: cancels exactly inside BN1 (affine-then-BN), unused.
  const float* bn1g  = (const float*)d_in[12];
  const float* bn1b  = (const float*)d_in[13];
  const float* bn2g  = (const float*)d_in[14];
  const float* bn2b  = (const float*)d_in[15];
  const float* denseW = (const float*)d_in[16];
  const float* denseb = (const float*)d_in[17];
  const float* ffW   = (const float*)d_in[18];
  const float* ffb   = (const float*)d_in[19];
  const float* outW  = (const float*)d_in[20];
  const float* outb  = (const float*)d_in[21];

  char* w = (char*)d_ws;
  float* x      = (float*)w; w += (size_t)N_ATOMS * FDIM * 4;   // 13.1 MB
  float* u      = (float*)w; w += (size_t)N_ATOMS * HDIM * 4;   // 26.2 MB
  float* v      = (float*)w; w += (size_t)N_ATOMS * HDIM * 4;   // 26.2 MB
  float* summed = (float*)w; w += (size_t)N_ATOMS * FDIM * 4;   // 13.1 MB
  float* part1  = (float*)w; w += (size_t)NBLK_CONV * 256 * 4;  // 1.6 MB
  float* part2  = (float*)w; w += (size_t)NBLK_CONV * 128 * 4;  // 0.8 MB
  float* sc1    = (float*)w; w += 256 * 4;
  float* sc2    = (float*)w; w += 128 * 4;
  float* cA     = (float*)w; w += 128 * 128 * 4;
  float* cB     = (float*)w; w += 128 * 128 * 4;
  (void)ws_size; (void)in_sizes; (void)n_in; (void)out_size;

  for (int br = 0; br < 2; ++br) {
    const float* afea = br ? afeaB : afeaA;
    const float* e    = br ? eB : eA;
    const int*   idx  = br ? idxB : idxA;
    const int*   cidx = br ? cidxB : cidxA;
    float* cOut = br ? cB : cA;
    k_embed<<<NBLK_EMB, 256, 0, stream>>>(afea, embW, embb, x);
    for (int L = 0; L < 3; ++L) {
      const float* W = fcW + (size_t)L * 169 * HDIM;
      k_uv<<<400, 256, 0, stream>>>(x, W, u, v);
      k_conv<false><<<NBLK_CONV, 256, 0, stream>>>(u, v, e, idx, W, nullptr, nullptr, part1);
      k_bn1<<<128, 64, 0, stream>>>(part1, bn1g + L * 128, bn1b + L * 128, sc1);
      k_conv<true><<<NBLK_CONV, 256, 0, stream>>>(u, v, e, idx, W, sc1, summed, part2);
      k_bn2<<<64, 64, 0, stream>>>(part2, bn2g + L * 64, bn2b + L * 64, sc2);
      k_p3<<<3200, 256, 0, stream>>>(x, summed, sc2);
    }
    k_pool<<<NCRYS, 128, 0, stream>>>(x, cidx, denseW, denseb, cOut);
  }
  k_final<<<NCRYS, 128, 0, stream>>>(cA, cB, ffW, ffb, outW, outb, (float*)d_out);
}